// Round 13
// baseline (147.772 us; speedup 1.0000x reference)
//
#include <hip/hip_runtime.h>
#include <math.h>

// Problem constants: B=2, S=2048, D=1024, H=16, DC=16, DH=64
typedef short short8 __attribute__((ext_vector_type(8)));
typedef short short4t __attribute__((ext_vector_type(4)));
typedef float f32x4  __attribute__((ext_vector_type(4)));

#define AS1 __attribute__((address_space(1)))
#define AS3 __attribute__((address_space(3)))

__device__ __forceinline__ unsigned cvt_pk_bf16(float lo, float hi) {
    unsigned r;
    asm("v_cvt_pk_bf16_f32 %0, %1, %2" : "=v"(r) : "v"(lo), "v"(hi));
    return r;
}
__device__ __forceinline__ unsigned f2bf_rne(float x) {
    unsigned u = __float_as_uint(x);
    return (u + 0x7fffu + ((u >> 16) & 1u)) >> 16;
}
__device__ __forceinline__ float exp2_fast(float x) {   // v_exp_f32 computes 2^x
    float r;
    asm("v_exp_f32 %0, %1" : "=v"(r) : "v"(x));
    return r;
}
// 16x16x16 bf16 MFMA (K=16): B-frag layout matches the 16x16 D-layout of the
// score MFMA, so P needs NO cross-lane redistribution before PV.
__device__ __forceinline__ f32x4 mfma_k16(short4t a, short4t b, f32x4 c) {
#if __has_builtin(__builtin_amdgcn_mfma_f32_16x16x16bf16_1k)
    return __builtin_amdgcn_mfma_f32_16x16x16bf16_1k(a, b, c, 0, 0, 0);
#else
    asm volatile("v_mfma_f32_16x16x16_bf16 %0, %1, %2, %0" : "+v"(c) : "v"(a), "v"(b));
    return c;
#endif
}

// ---------------------------------------------------------------------------
// fused fp32 -> bf16 converts: hidden (524288 chunks), Wv/Wo (131072 each),
// Wn (2048).  One launch, 3080 blocks; 8 elems/thread.
// ---------------------------------------------------------------------------
__global__ __launch_bounds__(256) void f2bf_all(const float* __restrict__ hidden,
                                                const float* __restrict__ Wv,
                                                const float* __restrict__ Wo,
                                                const float* __restrict__ Wn,
                                                short* __restrict__ hsb,
                                                short* __restrict__ Wvb,
                                                short* __restrict__ Wob,
                                                short* __restrict__ Wnb) {
    const int i = blockIdx.x * 256 + threadIdx.x;
    const float* src;
    short* dst;
    int ii;
    if (i < 524288)      { src = hidden; dst = hsb; ii = i; }
    else if (i < 655360) { src = Wv; dst = Wvb; ii = i - 524288; }
    else if (i < 786432) { src = Wo; dst = Wob; ii = i - 655360; }
    else                 { src = Wn; dst = Wnb; ii = i - 786432; }
    const float4 a = ((const float4*)src)[2 * ii];
    const float4 b = ((const float4*)src)[2 * ii + 1];
    uint4 r;
    r.x = cvt_pk_bf16(a.x, a.y);
    r.y = cvt_pk_bf16(a.z, a.w);
    r.z = cvt_pk_bf16(b.x, b.y);
    r.w = cvt_pk_bf16(b.z, b.w);
    ((uint4*)dst)[ii] = r;
}

// ---------------------------------------------------------------------------
// z = coords @ Wc.T + bc, per head h with ch = -softplus(gamma_h)*log2(e):
//   ZA[b,h,s,32] = [z(16), zsq, 1, 0...]          (keys / A-operand)
//   ZB[b,h,s,32] = [-2*ch*z(16), ch, ch*zsq, 0..] (queries / B-operand)
// => MFMA(ZA_k, ZB_q) = ch * (zsq_k + zsq_q - 2 z_k.z_q) = exp2 argument.
// ---------------------------------------------------------------------------
__global__ __launch_bounds__(256) void zker3(const float* __restrict__ coords,
                                             const float* __restrict__ Wc,
                                             const float* __restrict__ bc,
                                             const float* __restrict__ gamma,
                                             short* __restrict__ ZA,
                                             short* __restrict__ ZB) {
    const int bs = blockIdx.x;
    const int b = bs >> 11, s = bs & 2047;
    const int tid = threadIdx.x;
    __shared__ float csh[16];
    if (tid < 16) csh[tid] = coords[(size_t)bs * 16 + tid];
    __syncthreads();
    float z = bc[tid];
#pragma unroll
    for (int k = 0; k < 16; k++) z = fmaf(csh[k], Wc[tid * 16 + k], z);
    const unsigned ub = f2bf_rne(z);
    const float zb = __uint_as_float(ub << 16);
    float sq = zb * zb;
    sq += __shfl_xor(sq, 1, 64);
    sq += __shfl_xor(sq, 2, 64);
    sq += __shfl_xor(sq, 4, 64);
    sq += __shfl_xor(sq, 8, 64);
    const int h = tid >> 4, c = tid & 15;
    const float gm = gamma[h];
    const float sp = fmaxf(gm, 0.f) + log1pf(__expf(-fabsf(gm)));  // softplus
    const float ch = -sp * 1.4426950408889634f;                    // -g*log2(e)
    const size_t row = ((size_t)(b * 16 + h) * 2048 + s) * 32;
    ZA[row + c] = (short)ub;
    ZA[row + 16 + c] = (c == 0) ? (short)f2bf_rne(sq)
                                : (c == 1 ? (short)0x3F80 : (short)0);
    ZB[row + c] = (short)f2bf_rne(-2.f * ch * zb);
    ZB[row + 16 + c] = (c == 0) ? (short)f2bf_rne(ch)
                                : (c == 1 ? (short)f2bf_rne(ch * sq) : (short)0);
}

// ---------------------------------------------------------------------------
// bf16 MFMA GEMM: C[m,n] = sum_k A[m,k]*W[n,k] + bias[n].  M=4096,N=1024,K=1024
// 128x64 tile, BK=64 (16 MFMAs per barrier), 4 waves (2x2 of 64x32), LDS
// double-buffer via global_load_lds w16, chunk-XOR swizzle via pre-swizzled
// global source (rule #21).
// EPI=0: write V^T bf16 16-key-BLOCKED: per (b,h) panel of 128KB,
//        element (kc, dh, k) at kc*1024 + dh*16 + k  (kc = s>>4, k = s&15).
//        Attention reads this with wave-contiguous 512B loads.
// EPI=1: fp32 row-major [m,n]
// ---------------------------------------------------------------------------
template <int EPI>
__global__ __launch_bounds__(256) void gemm_mfma(const short* __restrict__ A,
                                                 const short* __restrict__ W,
                                                 const float* __restrict__ bias,
                                                 void* __restrict__ Cout) {
    __shared__ short As[2][128][64];
    __shared__ short Bs[2][64][64];
    const int tid = threadIdx.x;
    const int wv = tid >> 6, l = tid & 63, g = l >> 4, qc = l & 15;
    const int wm = wv >> 1, wn = wv & 1;
    const int Mb = blockIdx.y * 128, Nb = blockIdx.x * 64;

    auto stage = [&](int buf, int k0) {
#pragma unroll
        for (int i = 0; i < 4; i++) {                    // A: 1024 chunks, 4/thread
            const int c = i * 256 + tid;
            const int r = c >> 3, jp = c & 7;
            const int js = jp ^ (r & 7);                 // pre-swizzled source
            const short* gsA = A + (size_t)(Mb + r) * 1024 + k0 + js * 8;
            short* ldsA = &As[buf][0][0] + (size_t)(i * 256 + wv * 64) * 8;
            __builtin_amdgcn_global_load_lds((const AS1 void*)gsA, (AS3 void*)ldsA, 16, 0, 0);
        }
#pragma unroll
        for (int i = 0; i < 2; i++) {                    // B: 512 chunks, 2/thread
            const int c = i * 256 + tid;
            const int r = c >> 3, jp = c & 7;
            const int js = jp ^ (r & 7);
            const short* gsB = W + (size_t)(Nb + r) * 1024 + k0 + js * 8;
            short* ldsB = &Bs[buf][0][0] + (size_t)(i * 256 + wv * 64) * 8;
            __builtin_amdgcn_global_load_lds((const AS1 void*)gsB, (AS3 void*)ldsB, 16, 0, 0);
        }
    };

    f32x4 acc[4][2] = {};
    stage(0, 0);
    __syncthreads();
    int cur = 0;
#pragma unroll 1
    for (int kb = 0; kb < 16; kb++) {
        if (kb < 15) stage(cur ^ 1, (kb + 1) * 64);
#pragma unroll
        for (int ks = 0; ks < 2; ks++) {
            const int cs = ((ks * 4 + g) ^ (qc & 7)) * 8;   // swizzled read slot
            short8 af[4], bfr[2];
#pragma unroll
            for (int mt = 0; mt < 4; mt++)
                af[mt] = *(const short8*)&As[cur][wm * 64 + mt * 16 + qc][cs];
#pragma unroll
            for (int nt = 0; nt < 2; nt++)
                bfr[nt] = *(const short8*)&Bs[cur][wn * 32 + nt * 16 + qc][cs];
#pragma unroll
            for (int mt = 0; mt < 4; mt++)
#pragma unroll
                for (int nt = 0; nt < 2; nt++)
                    acc[mt][nt] = __builtin_amdgcn_mfma_f32_16x16x32_bf16(af[mt], bfr[nt], acc[mt][nt], 0, 0, 0);
        }
        __syncthreads();
        cur ^= 1;
    }

    float bl[2];
#pragma unroll
    for (int nt = 0; nt < 2; nt++) bl[nt] = bias[Nb + wn * 32 + nt * 16 + qc];
#pragma unroll
    for (int mt = 0; mt < 4; mt++) {
#pragma unroll
        for (int nt = 0; nt < 2; nt++) {
            const int m0 = Mb + wm * 64 + mt * 16 + g * 4;
            const int n  = Nb + wn * 32 + nt * 16 + qc;
            f32x4 v = acc[mt][nt];
            v = v + bl[nt];
            if (EPI == 0) {
                const int bb = m0 >> 11, s0 = m0 & 2047;
                const int hh = n >> 6, dh = n & 63;
                const int kc = s0 >> 4, si = s0 & 15;   // si = g*4, uint2-aligned
                uint2 p2;
                p2.x = cvt_pk_bf16(v[0], v[1]);
                p2.y = cvt_pk_bf16(v[2], v[3]);
                *(uint2*)((short*)Cout + (size_t)(bb * 16 + hh) * 131072 + kc * 1024 + dh * 16 + si) = p2;
            } else {
                float* C = (float*)Cout;
#pragma unroll
                for (int i = 0; i < 4; i++) C[(size_t)(m0 + i) * 1024 + n] = v[i];
            }
        }
    }
}

// ---------------------------------------------------------------------------
// Fused MFMA flash attention (v11): NO LDS, NO barriers.  Every load is
// wave-contiguous from global (zk: 1KB/instr; vf: 512B/instr via the
// 16-key-blocked V^T layout) so L1 serves the block's 4-wave reuse and L2
// the rest (working set 384KB/bh, XCD-swizzled).  Waves are fully
// independent; latency hidden by register prefetch: zk(i+1) + vf(i) issued
// before score-MFMA/exp2 (~200 cyc cover).  l = VALU running sum.
// 16 q/wave, 64 q/block, 1024 blocks XCD-swizzled.
// ---------------------------------------------------------------------------
__global__ __launch_bounds__(256, 4) void attn_mfma11(const short* __restrict__ ZAg,
                                                      const short* __restrict__ ZBg,
                                                      const short* __restrict__ Vt,
                                                      short* __restrict__ AOb) {
    const int tid = threadIdx.x;
    const int wv = tid >> 6, ln = tid & 63, g = ln >> 4, qc = ln & 15;
    const int lin = blockIdx.x;
    const int work = (lin & 7) * 128 + (lin >> 3);   // bijective, 1024 % 8 == 0
    const int qb = work & 31, h = (work >> 5) & 15, b = work >> 9;
    const int bh = b * 16 + h;
    const int q0 = qb * 64 + wv * 16;

    const short* ZAb = ZAg + (size_t)bh * (2048 * 32);
    const short* ZBb = ZBg + (size_t)bh * (2048 * 32);
    const short* Vb  = Vt  + (size_t)bh * 131072;

    const short8 zq = *(const short8*)(ZBb + (size_t)(q0 + qc) * 32 + g * 8);

    f32x4 acc[4] = {};
    float lsum = 0.f;

    // per-lane bases; loop offsets are linear in i
    const short* zbase = ZAb + (size_t)qc * 32 + g * 8;   // + (kb + kt*16)*32
    const short* vbase = Vb + qc * 16 + g * 4;            // + (i*4 + kt)*1024 + mt*256

    short8 zkc[4];
#pragma unroll
    for (int kt = 0; kt < 4; kt++)
        zkc[kt] = *(const short8*)(zbase + (size_t)(kt * 16) * 32);

#pragma unroll 1
    for (int i = 0; i < 32; i++) {
        const int kb = i * 64;

        // prefetch next z-tile (consumed next iteration)
        short8 zkn[4];
        if (i < 31) {
#pragma unroll
            for (int kt = 0; kt < 4; kt++)
                zkn[kt] = *(const short8*)(zbase + (size_t)(kb + 64 + kt * 16) * 32);
        }

        // issue this tile's V fragments (cover: score MFMA + exp2 block)
        short4t vf[4][4];
        const short* vk = vbase + (size_t)(i * 4) * 1024;
#pragma unroll
        for (int kt = 0; kt < 4; kt++)
#pragma unroll
            for (int mt = 0; mt < 4; mt++)
                vf[kt][mt] = *(const short4t*)(vk + kt * 1024 + mt * 256);

        // scores
        const f32x4 z4 = {0.f, 0.f, 0.f, 0.f};
        f32x4 S[4];
        __builtin_amdgcn_s_setprio(1);
#pragma unroll
        for (int kt = 0; kt < 4; kt++)
            S[kt] = __builtin_amdgcn_mfma_f32_16x16x32_bf16(zkc[kt], zq, z4, 0, 0, 0);
        __builtin_amdgcn_s_setprio(0);

        // p = exp2(min(S,0)); accumulate l; pack -> K=16 B-fragments
        unsigned pk[4][2];
#pragma unroll
        for (int kt = 0; kt < 4; kt++) {
            const float p0 = exp2_fast(fminf(S[kt][0], 0.f));
            const float p1 = exp2_fast(fminf(S[kt][1], 0.f));
            const float p2 = exp2_fast(fminf(S[kt][2], 0.f));
            const float p3 = exp2_fast(fminf(S[kt][3], 0.f));
            lsum += (p0 + p1) + (p2 + p3);
            pk[kt][0] = cvt_pk_bf16(p0, p1);
            pk[kt][1] = cvt_pk_bf16(p2, p3);
        }

        // PV via K=16 MFMAs (A = blocked V^T frag, B = packed P directly)
        __builtin_amdgcn_s_setprio(1);
#pragma unroll
        for (int kt = 0; kt < 4; kt++) {
            union { unsigned u[2]; short4t s4; } pb;
            pb.u[0] = pk[kt][0];
            pb.u[1] = pk[kt][1];
#pragma unroll
            for (int mt = 0; mt < 4; mt++)
                acc[mt] = mfma_k16(vf[kt][mt], pb.s4, acc[mt]);
        }
        __builtin_amdgcn_s_setprio(0);

        if (i < 31) {
#pragma unroll
            for (int kt = 0; kt < 4; kt++) zkc[kt] = zkn[kt];
        }
    }

    // epilogue: full l(qc) = sum over the 4 g-lane groups
    lsum += __shfl_xor(lsum, 16, 64);
    lsum += __shfl_xor(lsum, 32, 64);
    const float inv = 1.f / lsum;
    const size_t row = (size_t)(b * 2048 + q0 + qc) * 1024 + h * 64;
#pragma unroll
    for (int mt = 0; mt < 4; mt++) {
        uint2 o;
        o.x = cvt_pk_bf16(acc[mt][0] * inv, acc[mt][1] * inv);
        o.y = cvt_pk_bf16(acc[mt][2] * inv, acc[mt][3] * inv);
        *(uint2*)(AOb + row + mt * 16 + g * 4) = o;
    }
}

// ---------------------------------------------------------------------------
// updated_coords = hsb(bf16) @ Wnb.T + bn via MFMA.  M=4096, N=16, K=1024.
// Runs BEFORE attn overwrites hsb (AOb alias).
// ---------------------------------------------------------------------------
__global__ __launch_bounds__(256) void coords_mfma(const short* __restrict__ A,
                                                   const short* __restrict__ Wnb,
                                                   const float* __restrict__ bn,
                                                   float* __restrict__ out1) {
    __shared__ float red[4][16][16];
    const int tid = threadIdx.x;
    const int wv = tid >> 6, l = tid & 63, g = l >> 4, qc = l & 15;
    const int m0 = blockIdx.x * 16;
    const int k0 = wv * 256;
    f32x4 acc = {};
#pragma unroll
    for (int kk = 0; kk < 256; kk += 32) {
        const short8 af = *(const short8*)(A + (size_t)(m0 + qc) * 1024 + k0 + kk + g * 8);
        const short8 bf = *(const short8*)(Wnb + (size_t)qc * 1024 + k0 + kk + g * 8);
        acc = __builtin_amdgcn_mfma_f32_16x16x32_bf16(af, bf, acc, 0, 0, 0);
    }
#pragma unroll
    for (int i2 = 0; i2 < 4; i2++) red[wv][g * 4 + i2][qc] = acc[i2];
    __syncthreads();
    const int r = tid >> 4, c = tid & 15;
    const float s = red[0][r][c] + red[1][r][c] + red[2][r][c] + red[3][r][c] + bn[c];
    out1[(size_t)(m0 + r) * 16 + c] = s;
}

// ---------------------------------------------------------------------------
extern "C" void kernel_launch(void* const* d_in, const int* in_sizes, int n_in,
                              void* d_out, int out_size, void* d_ws, size_t ws_size,
                              hipStream_t stream) {
    (void)in_sizes; (void)n_in; (void)out_size; (void)ws_size;
    const float* hidden = (const float*)d_in[0];
    const float* coords = (const float*)d_in[1];
    const float* Wv = (const float*)d_in[2];
    const float* bv = (const float*)d_in[3];
    const float* Wc = (const float*)d_in[4];
    const float* bc = (const float*)d_in[5];
    const float* Wn = (const float*)d_in[6];
    const float* bn = (const float*)d_in[7];
    const float* Wo = (const float*)d_in[8];
    const float* bo = (const float*)d_in[9];
    const float* gamma = (const float*)d_in[10];

    char* wsb = (char*)d_ws;
    short* hsb = (short*)(wsb);                    // 0..8 MB  [4096,1024] bf16
    short* AOb = hsb;                              // aliases hsb (hsb dead after coords_mfma)
    short* Wvb = (short*)(wsb + (8 << 20));        // 8..10 MB
    short* Wob = (short*)(wsb + (10 << 20));       // 10..12 MB
    short* Vt  = (short*)(wsb + (12 << 20));       // 12..20 MB [b,h] 16-key-blocked V^T
    short* ZA  = (short*)(wsb + (20 << 20));       // 20..24 MB [b,h,s,32] bf16
    short* ZB  = (short*)(wsb + (24 << 20));       // 24..28 MB [b,h,s,32] bf16
    short* Wnb = (short*)(wsb + (28 << 20));       // 28 MB + 32 KB [16,1024] bf16

    float* out_hidden = (float*)d_out;             // [B,S,D]
    float* out_coords = out_hidden + 4194304;      // [B,S,CD]

    f2bf_all<<<3080, 256, 0, stream>>>(hidden, Wv, Wo, Wn, hsb, Wvb, Wob, Wnb);
    zker3<<<4096, 256, 0, stream>>>(coords, Wc, bc, gamma, ZA, ZB);
    gemm_mfma<0><<<dim3(16, 32), 256, 0, stream>>>(hsb, Wvb, bv, (void*)Vt);
    coords_mfma<<<256, 256, 0, stream>>>(hsb, Wnb, bn, out_coords);
    attn_mfma11<<<1024, 256, 0, stream>>>(ZA, ZB, Vt, AOb);
    gemm_mfma<1><<<dim3(16, 32), 256, 0, stream>>>(AOb, Wob, bo, (void*)out_hidden);
}

// Round 14
// 106.858 us; speedup vs baseline: 1.3829x; 1.3829x over previous
//
#include <hip/hip_runtime.h>
#include <math.h>

// Problem constants: B=2, S=2048, D=1024, H=16, DC=16, DH=64
typedef short short8 __attribute__((ext_vector_type(8)));
typedef short short4t __attribute__((ext_vector_type(4)));
typedef float f32x4  __attribute__((ext_vector_type(4)));

#define AS1 __attribute__((address_space(1)))
#define AS3 __attribute__((address_space(3)))

__device__ __forceinline__ unsigned cvt_pk_bf16(float lo, float hi) {
    unsigned r;
    asm("v_cvt_pk_bf16_f32 %0, %1, %2" : "=v"(r) : "v"(lo), "v"(hi));
    return r;
}
__device__ __forceinline__ unsigned f2bf_rne(float x) {
    unsigned u = __float_as_uint(x);
    return (u + 0x7fffu + ((u >> 16) & 1u)) >> 16;
}
__device__ __forceinline__ float exp2_fast(float x) {   // v_exp_f32 computes 2^x
    float r;
    asm("v_exp_f32 %0, %1" : "=v"(r) : "v"(x));
    return r;
}
// 16x16x16 bf16 MFMA (K=16): B-frag layout matches the 16x16 D-layout of the
// score MFMA, so P needs NO cross-lane redistribution before PV.
__device__ __forceinline__ f32x4 mfma_k16(short4t a, short4t b, f32x4 c) {
#if __has_builtin(__builtin_amdgcn_mfma_f32_16x16x16bf16_1k)
    return __builtin_amdgcn_mfma_f32_16x16x16bf16_1k(a, b, c, 0, 0, 0);
#else
    asm volatile("v_mfma_f32_16x16x16_bf16 %0, %1, %2, %0" : "+v"(c) : "v"(a), "v"(b));
    return c;
#endif
}

// ---------------------------------------------------------------------------
// fused fp32 -> bf16 converts: hidden (524288 chunks), Wv/Wo (131072 each),
// Wn (2048).  One launch, 3080 blocks; 8 elems/thread.
// ---------------------------------------------------------------------------
__global__ __launch_bounds__(256) void f2bf_all(const float* __restrict__ hidden,
                                                const float* __restrict__ Wv,
                                                const float* __restrict__ Wo,
                                                const float* __restrict__ Wn,
                                                short* __restrict__ hsb,
                                                short* __restrict__ Wvb,
                                                short* __restrict__ Wob,
                                                short* __restrict__ Wnb) {
    const int i = blockIdx.x * 256 + threadIdx.x;
    const float* src;
    short* dst;
    int ii;
    if (i < 524288)      { src = hidden; dst = hsb; ii = i; }
    else if (i < 655360) { src = Wv; dst = Wvb; ii = i - 524288; }
    else if (i < 786432) { src = Wo; dst = Wob; ii = i - 655360; }
    else                 { src = Wn; dst = Wnb; ii = i - 786432; }
    const float4 a = ((const float4*)src)[2 * ii];
    const float4 b = ((const float4*)src)[2 * ii + 1];
    uint4 r;
    r.x = cvt_pk_bf16(a.x, a.y);
    r.y = cvt_pk_bf16(a.z, a.w);
    r.z = cvt_pk_bf16(b.x, b.y);
    r.w = cvt_pk_bf16(b.z, b.w);
    ((uint4*)dst)[ii] = r;
}

// ---------------------------------------------------------------------------
// z = coords @ Wc.T + bc, per head h with ch = -softplus(gamma_h)*log2(e):
//   ZA[b,h,s,32] = [z(16), zsq, 1, 0...]          (keys / A-operand)
//   ZB[b,h,s,32] = [-2*ch*z(16), ch, ch*zsq, 0..] (queries / B-operand)
// => MFMA(ZA_k, ZB_q) = ch * (zsq_k + zsq_q - 2 z_k.z_q) = exp2 argument.
// ---------------------------------------------------------------------------
__global__ __launch_bounds__(256) void zker3(const float* __restrict__ coords,
                                             const float* __restrict__ Wc,
                                             const float* __restrict__ bc,
                                             const float* __restrict__ gamma,
                                             short* __restrict__ ZA,
                                             short* __restrict__ ZB) {
    const int bs = blockIdx.x;
    const int b = bs >> 11, s = bs & 2047;
    const int tid = threadIdx.x;
    __shared__ float csh[16];
    if (tid < 16) csh[tid] = coords[(size_t)bs * 16 + tid];
    __syncthreads();
    float z = bc[tid];
#pragma unroll
    for (int k = 0; k < 16; k++) z = fmaf(csh[k], Wc[tid * 16 + k], z);
    const unsigned ub = f2bf_rne(z);
    const float zb = __uint_as_float(ub << 16);
    float sq = zb * zb;
    sq += __shfl_xor(sq, 1, 64);
    sq += __shfl_xor(sq, 2, 64);
    sq += __shfl_xor(sq, 4, 64);
    sq += __shfl_xor(sq, 8, 64);
    const int h = tid >> 4, c = tid & 15;
    const float gm = gamma[h];
    const float sp = fmaxf(gm, 0.f) + log1pf(__expf(-fabsf(gm)));  // softplus
    const float ch = -sp * 1.4426950408889634f;                    // -g*log2(e)
    const size_t row = ((size_t)(b * 16 + h) * 2048 + s) * 32;
    ZA[row + c] = (short)ub;
    ZA[row + 16 + c] = (c == 0) ? (short)f2bf_rne(sq)
                                : (c == 1 ? (short)0x3F80 : (short)0);
    ZB[row + c] = (short)f2bf_rne(-2.f * ch * zb);
    ZB[row + 16 + c] = (c == 0) ? (short)f2bf_rne(ch)
                                : (c == 1 ? (short)f2bf_rne(ch * sq) : (short)0);
}

// ---------------------------------------------------------------------------
// bf16 MFMA GEMM: C[m,n] = sum_k A[m,k]*W[n,k] + bias[n].  M=4096,N=1024,K=1024
// 128x64 tile, BK=64 (16 MFMAs per barrier), 4 waves (2x2 of 64x32), LDS
// double-buffer via global_load_lds w16, chunk-XOR swizzle via pre-swizzled
// global source (rule #21).  1D grid with bijective XCD swizzle so each XCD
// owns 2 N-panels (weight panel L2-resident, reused by its 32 M-tiles).
// EPI=0: write V^T bf16 [b,h,dh,s] with the 8B-half swap (dh bit3).
// EPI=1: fp32 row-major [m,n]
// ---------------------------------------------------------------------------
template <int EPI>
__global__ __launch_bounds__(256) void gemm_mfma(const short* __restrict__ A,
                                                 const short* __restrict__ W,
                                                 const float* __restrict__ bias,
                                                 void* __restrict__ Cout) {
    __shared__ short As[2][128][64];
    __shared__ short Bs[2][64][64];
    const int tid = threadIdx.x;
    const int wv = tid >> 6, l = tid & 63, g = l >> 4, qc = l & 15;
    const int wm = wv >> 1, wn = wv & 1;
    const int lin = blockIdx.x;                       // 512 blocks
    const int wid = (lin & 7) * 64 + (lin >> 3);      // bijective XCD swizzle
    const int Mb = (wid & 31) * 128, Nb = (wid >> 5) * 64;

    auto stage = [&](int buf, int k0) {
#pragma unroll
        for (int i = 0; i < 4; i++) {                    // A: 1024 chunks, 4/thread
            const int c = i * 256 + tid;
            const int r = c >> 3, jp = c & 7;
            const int js = jp ^ (r & 7);                 // pre-swizzled source
            const short* gsA = A + (size_t)(Mb + r) * 1024 + k0 + js * 8;
            short* ldsA = &As[buf][0][0] + (size_t)(i * 256 + wv * 64) * 8;
            __builtin_amdgcn_global_load_lds((const AS1 void*)gsA, (AS3 void*)ldsA, 16, 0, 0);
        }
#pragma unroll
        for (int i = 0; i < 2; i++) {                    // B: 512 chunks, 2/thread
            const int c = i * 256 + tid;
            const int r = c >> 3, jp = c & 7;
            const int js = jp ^ (r & 7);
            const short* gsB = W + (size_t)(Nb + r) * 1024 + k0 + js * 8;
            short* ldsB = &Bs[buf][0][0] + (size_t)(i * 256 + wv * 64) * 8;
            __builtin_amdgcn_global_load_lds((const AS1 void*)gsB, (AS3 void*)ldsB, 16, 0, 0);
        }
    };

    f32x4 acc[4][2] = {};
    stage(0, 0);
    __syncthreads();
    int cur = 0;
#pragma unroll 1
    for (int kb = 0; kb < 16; kb++) {
        if (kb < 15) stage(cur ^ 1, (kb + 1) * 64);
#pragma unroll
        for (int ks = 0; ks < 2; ks++) {
            const int cs = ((ks * 4 + g) ^ (qc & 7)) * 8;   // swizzled read slot
            short8 af[4], bfr[2];
#pragma unroll
            for (int mt = 0; mt < 4; mt++)
                af[mt] = *(const short8*)&As[cur][wm * 64 + mt * 16 + qc][cs];
#pragma unroll
            for (int nt = 0; nt < 2; nt++)
                bfr[nt] = *(const short8*)&Bs[cur][wn * 32 + nt * 16 + qc][cs];
#pragma unroll
            for (int mt = 0; mt < 4; mt++)
#pragma unroll
                for (int nt = 0; nt < 2; nt++)
                    acc[mt][nt] = __builtin_amdgcn_mfma_f32_16x16x32_bf16(af[mt], bfr[nt], acc[mt][nt], 0, 0, 0);
        }
        __syncthreads();
        cur ^= 1;
    }

    float bl[2];
#pragma unroll
    for (int nt = 0; nt < 2; nt++) bl[nt] = bias[Nb + wn * 32 + nt * 16 + qc];
#pragma unroll
    for (int mt = 0; mt < 4; mt++) {
#pragma unroll
        for (int nt = 0; nt < 2; nt++) {
            const int m0 = Mb + wm * 64 + mt * 16 + g * 4;
            const int n  = Nb + wn * 32 + nt * 16 + qc;
            f32x4 v = acc[mt][nt];
            v = v + bl[nt];
            if (EPI == 0) {
                const int bb = m0 >> 11, s0 = m0 & 2047;
                const int hh = n >> 6, dh = n & 63;
                const int s0x = s0 ^ (((n >> 3) & 1) << 2);   // 8B-half swap for dh bit3
                uint2 p2;
                p2.x = cvt_pk_bf16(v[0], v[1]);
                p2.y = cvt_pk_bf16(v[2], v[3]);
                *(uint2*)((short*)Cout + (size_t)((bb * 16 + hh) * 64 + dh) * 2048 + s0x) = p2;
            } else {
                float* C = (float*)Cout;
#pragma unroll
                for (int i = 0; i < 4; i++) C[(size_t)(m0 + i) * 1024 + n] = v[i];
            }
        }
    }
}

// ---------------------------------------------------------------------------
// Fused MFMA flash attention (v12 = round-10 v8 + pk double-buffer unroll):
//  * Conflict-free LDS layouts: chunk-permuted Z (wave reads are contiguous
//    1KB), half-swapped V (b64 A-frag reads 2-way max) — conflicts == 0.
//  * T15 pipeline: S(i+1)+exp2+pack (VALU) overlaps PV(i) (MFMA); pkA/pkB
//    named double-buffer via explicit 2-step unroll (no per-iter reg copies,
//    rule #20-safe static indexing).
//  * l via ones-row K=16 MFMA (measured faster than VALU sum, r12).
//  * All staging via global_load_lds (async DMA), drained by the barrier.
// 16 q/wave, 64 q/block, 1024 blocks XCD-swizzled, 4 blocks/CU.
// ---------------------------------------------------------------------------
__global__ __launch_bounds__(256, 4) void attn_mfma12(const short* __restrict__ ZAg,
                                                      const short* __restrict__ ZBg,
                                                      const short* __restrict__ Vt,
                                                      short* __restrict__ AOb) {
    __shared__ short Vs[2][4096];   // V tile [j 0..7][dh 0..63] 16B slots, dbuf
    __shared__ short Zs[4][2048];   // Z tile, chunk-permuted, 4-deep ring
    const int tid = threadIdx.x;
    const int wv = tid >> 6, ln = tid & 63, g = ln >> 4, qc = ln & 15;
    const int lin = blockIdx.x;
    const int work = (lin & 7) * 128 + (lin >> 3);   // bijective, 1024 % 8 == 0
    const int qb = work & 31, h = (work >> 5) & 15, b = work >> 9;
    const int bh = b * 16 + h;
    const int q0 = qb * 64 + wv * 16;

    const short* ZAb = ZAg + (size_t)bh * (2048 * 32);
    const short* ZBb = ZBg + (size_t)bh * (2048 * 32);
    const short* Vb  = Vt  + (size_t)bh * (64 * 2048);

    const short8 zq = *(const short8*)(ZBb + (size_t)(q0 + qc) * 32 + g * 8);

    union { unsigned u[2]; short4t s4; } ones4;
    ones4.u[0] = ones4.u[1] = (qc == 0) ? 0x3F803F80u : 0u;  // A row 0 = ones

    f32x4 acc[4] = {};
    f32x4 accl = {};

    // staging bases (thread-linear dests per rule #21)
    const short* gvb = Vb + (size_t)ln * 2048 + wv * 8;
    short* lvd = &Vs[0][0] + (size_t)tid * 8;
    short* lzd = &Zs[0][0] + (size_t)tid * 8;
    // Z source permutation: thread tid stages LDS chunk tid; content is
    // (row = z_kt*16 + z_r, 8-short group z_g) of the tile.
    const int z_kt = tid >> 6, z_g = (tid >> 4) & 3, z_r = tid & 15;

    auto stageV = [&](int buf, int kb) {
        const short* gv = gvb + kb;
        short* lvb = lvd + buf * 4096;
        __builtin_amdgcn_global_load_lds((const AS1 void*)gv, (AS3 void*)lvb, 16, 0, 0);
        __builtin_amdgcn_global_load_lds((const AS1 void*)(gv + 32), (AS3 void*)(lvb + 2048), 16, 0, 0);
    };
    auto stageZ = [&](int buf, int kb) {
        const short* gz = ZAb + (size_t)(kb + z_kt * 16 + z_r) * 32 + z_g * 8;
        __builtin_amdgcn_global_load_lds((const AS1 void*)gz, (AS3 void*)(lzd + buf * 2048), 16, 0, 0);
    };

    // per-lane read bases (further offsets are compile-time immediates)
    const int vrd = (((g >> 1) * 64 + qc) * 8) + (((g & 1) ^ ((qc >> 3) & 1)) << 2);
    const int zrd = g * 128 + qc * 8;   // chunk g*16+qc of each 16-row group

    // S(tile)+exp2+pack from Z ring slot zbuf
    auto computeP = [&](int zbuf, unsigned pko[4][2]) {
        const short* Zc = &Zs[0][0] + zbuf * 2048;
        short8 zk[4];
#pragma unroll
        for (int kt = 0; kt < 4; kt++)
            zk[kt] = *(const short8*)(Zc + zrd + kt * 512);
        const f32x4 z4 = {0.f, 0.f, 0.f, 0.f};
#pragma unroll
        for (int kt = 0; kt < 4; kt++) {
            const f32x4 S = __builtin_amdgcn_mfma_f32_16x16x32_bf16(zk[kt], zq, z4, 0, 0, 0);
            pko[kt][0] = cvt_pk_bf16(exp2_fast(fminf(S[0], 0.f)), exp2_fast(fminf(S[1], 0.f)));
            pko[kt][1] = cvt_pk_bf16(exp2_fast(fminf(S[2], 0.f)), exp2_fast(fminf(S[3], 0.f)));
        }
    };
    // PV + l for one tile from Vs buffer `buf` using packed P
    auto doPV = [&](int buf, unsigned pkk[4][2]) {
        const short* Vc = &Vs[buf][0];
        __builtin_amdgcn_s_setprio(1);
#pragma unroll
        for (int kt = 0; kt < 4; kt++) {
            union { unsigned u[2]; short4t s4; } pb;
            pb.u[0] = pkk[kt][0];
            pb.u[1] = pkk[kt][1];
            accl = mfma_k16(ones4.s4, pb.s4, accl);
#pragma unroll
            for (int mt = 0; mt < 4; mt++)
                acc[mt] = mfma_k16(*(const short4t*)(Vc + vrd + kt * 1024 + mt * 128),
                                   pb.s4, acc[mt]);
        }
        __builtin_amdgcn_s_setprio(0);
    };

    // prologue: V(0), Z(0), Z(1); compute pkA(tile 0)
    stageV(0, 0);
    stageZ(0, 0);
    stageZ(1, 64);
    __syncthreads();

    unsigned pkA[4][2], pkB[4][2];
    computeP(0, pkA);

    int cur = 0;
#pragma unroll 1
    for (int i = 0; i < 32; i += 2) {
        // ---- even step: consume pkA (tile i), produce pkB (tile i+1) ----
        if (i < 31) stageV(cur ^ 1, (i + 1) * 64);
        if (i < 30) stageZ((i + 2) & 3, (i + 2) * 64);
        computeP((i + 1) & 3, pkB);
        doPV(cur, pkA);
        __syncthreads();
        cur ^= 1;
        // ---- odd step: consume pkB (tile i+1), produce pkA (tile i+2) ----
        if (i + 1 < 31) stageV(cur ^ 1, (i + 2) * 64);
        if (i + 1 < 30) stageZ((i + 3) & 3, (i + 3) * 64);
        computeP((i + 2) & 3, pkA);   // last pair: stale slot, result unused
        doPV(cur, pkB);
        __syncthreads();
        cur ^= 1;
    }

    // epilogue: l sits at D(row0,col qc) = lane qc, reg 0
    const float lv2 = __shfl(accl[0], qc, 64);
    const float inv = 1.f / lv2;
    const size_t row = (size_t)(b * 2048 + q0 + qc) * 1024 + h * 64;
#pragma unroll
    for (int mt = 0; mt < 4; mt++) {
        uint2 o;
        o.x = cvt_pk_bf16(acc[mt][0] * inv, acc[mt][1] * inv);
        o.y = cvt_pk_bf16(acc[mt][2] * inv, acc[mt][3] * inv);
        *(uint2*)(AOb + row + mt * 16 + g * 4) = o;
    }
}

// ---------------------------------------------------------------------------
// updated_coords = hsb(bf16) @ Wnb.T + bn via MFMA.  M=4096, N=16, K=1024.
// Runs BEFORE attn overwrites hsb (AOb alias).
// ---------------------------------------------------------------------------
__global__ __launch_bounds__(256) void coords_mfma(const short* __restrict__ A,
                                                   const short* __restrict__ Wnb,
                                                   const float* __restrict__ bn,
                                                   float* __restrict__ out1) {
    __shared__ float red[4][16][16];
    const int tid = threadIdx.x;
    const int wv = tid >> 6, l = tid & 63, g = l >> 4, qc = l & 15;
    const int m0 = blockIdx.x * 16;
    const int k0 = wv * 256;
    f32x4 acc = {};
#pragma unroll
    for (int kk = 0; kk < 256; kk += 32) {
        const short8 af = *(const short8*)(A + (size_t)(m0 + qc) * 1024 + k0 + kk + g * 8);
        const short8 bf = *(const short8*)(Wnb + (size_t)qc * 1024 + k0 + kk + g * 8);
        acc = __builtin_amdgcn_mfma_f32_16x16x32_bf16(af, bf, acc, 0, 0, 0);
    }
#pragma unroll
    for (int i2 = 0; i2 < 4; i2++) red[wv][g * 4 + i2][qc] = acc[i2];
    __syncthreads();
    const int r = tid >> 4, c = tid & 15;
    const float s = red[0][r][c] + red[1][r][c] + red[2][r][c] + red[3][r][c] + bn[c];
    out1[(size_t)(m0 + r) * 16 + c] = s;
}

// ---------------------------------------------------------------------------
extern "C" void kernel_launch(void* const* d_in, const int* in_sizes, int n_in,
                              void* d_out, int out_size, void* d_ws, size_t ws_size,
                              hipStream_t stream) {
    (void)in_sizes; (void)n_in; (void)out_size; (void)ws_size;
    const float* hidden = (const float*)d_in[0];
    const float* coords = (const float*)d_in[1];
    const float* Wv = (const float*)d_in[2];
    const float* bv = (const float*)d_in[3];
    const float* Wc = (const float*)d_in[4];
    const float* bc = (const float*)d_in[5];
    const float* Wn = (const float*)d_in[6];
    const float* bn = (const float*)d_in[7];
    const float* Wo = (const float*)d_in[8];
    const float* bo = (const float*)d_in[9];
    const float* gamma = (const float*)d_in[10];

    char* wsb = (char*)d_ws;
    short* hsb = (short*)(wsb);                    // 0..8 MB  [4096,1024] bf16
    short* AOb = hsb;                              // aliases hsb (hsb dead after coords_mfma)
    short* Wvb = (short*)(wsb + (8 << 20));        // 8..10 MB
    short* Wob = (short*)(wsb + (10 << 20));       // 10..12 MB
    short* Vt  = (short*)(wsb + (12 << 20));       // 12..20 MB [b,h,dh,s] bf16 (half-swapped)
    short* ZA  = (short*)(wsb + (20 << 20));       // 20..24 MB [b,h,s,32] bf16
    short* ZB  = (short*)(wsb + (24 << 20));       // 24..28 MB [b,h,s,32] bf16
    short* Wnb = (short*)(wsb + (28 << 20));       // 28 MB + 32 KB [16,1024] bf16

    float* out_hidden = (float*)d_out;             // [B,S,D]
    float* out_coords = out_hidden + 4194304;      // [B,S,CD]

    f2bf_all<<<3080, 256, 0, stream>>>(hidden, Wv, Wo, Wn, hsb, Wvb, Wob, Wnb);
    zker3<<<4096, 256, 0, stream>>>(coords, Wc, bc, gamma, ZA, ZB);
    gemm_mfma<0><<<512, 256, 0, stream>>>(hsb, Wvb, bv, (void*)Vt);
    coords_mfma<<<256, 256, 0, stream>>>(hsb, Wnb, bn, out_coords);
    attn_mfma12<<<1024, 256, 0, stream>>>(ZA, ZB, Vt, AOb);
    gemm_mfma<1><<<512, 256, 0, stream>>>(AOb, Wob, bo, (void*)out_hidden);
}